// Round 1
// baseline (358.222 us; speedup 1.0000x reference)
//
#include <hip/hip_runtime.h>

typedef unsigned short u16;
typedef __attribute__((ext_vector_type(8))) short short8;
typedef __attribute__((ext_vector_type(4))) float f32x4;
typedef __attribute__((ext_vector_type(4))) u16 u16x4;

#define F 256

__device__ __forceinline__ u16 f2bf(float f) {
  // round-to-nearest-even fp32 -> bf16 bits
  unsigned u = __float_as_uint(f);
  unsigned r = u + 0x7fffu + ((u >> 16) & 1u);
  return (u16)(r >> 16);
}

__global__ void zero_int(int* __restrict__ p, int n) {
  int i = blockIdx.x * 256 + threadIdx.x;
  if (i < n) p[i] = 0;
}

// counts[row+1]++ ; counts[0] stays 0
__global__ void hist_k(const int* __restrict__ erow, int* __restrict__ off, int E) {
  int e = blockIdx.x * 256 + threadIdx.x;
  if (e < E) atomicAdd(&off[erow[e] + 1], 1);
}

// in-place inclusive scan per 256-block, block totals to blks[]
__global__ void scan1_k(int* __restrict__ a, int* __restrict__ blks, int n) {
  __shared__ int s[256];
  int t = threadIdx.x;
  int i = blockIdx.x * 256 + t;
  s[t] = (i < n) ? a[i] : 0;
  __syncthreads();
  for (int d = 1; d < 256; d <<= 1) {
    int v = (t >= d) ? s[t - d] : 0;
    __syncthreads();
    s[t] += v;
    __syncthreads();
  }
  if (i < n) a[i] = s[t];
  if (t == 255) blks[blockIdx.x] = s[255];
}

// exclusive scan of block sums (nb <= 256), single block
__global__ void scan2_k(int* __restrict__ blks, int nb) {
  __shared__ int s[256];
  int t = threadIdx.x;
  s[t] = (t < nb) ? blks[t] : 0;
  __syncthreads();
  for (int d = 1; d < 256; d <<= 1) {
    int v = (t >= d) ? s[t - d] : 0;
    __syncthreads();
    s[t] += v;
    __syncthreads();
  }
  if (t < nb) blks[t] = (t == 0) ? 0 : s[t - 1];
}

// add block offsets; also init cursor = node start
__global__ void scan3_k(int* __restrict__ a, const int* __restrict__ blks,
                        int* __restrict__ cur, int n, int nn) {
  int i = blockIdx.x * 256 + threadIdx.x;
  if (i < n) {
    int v = a[i] + blks[blockIdx.x];
    a[i] = v;
    if (i < nn) cur[i] = v;
  }
}

// bucket edges into CSR (col,val) via atomic cursor
__global__ void scatter_k(const int* __restrict__ erow, const int* __restrict__ ecol,
                          const float* __restrict__ eval, int* __restrict__ cur,
                          int* __restrict__ ccol, float* __restrict__ cv, int E) {
  int e = blockIdx.x * 256 + threadIdx.x;
  if (e < E) {
    int r = erow[e];
    int p = atomicAdd(&cur[r], 1);
    ccol[p] = ecol[e];
    cv[p] = eval[e];
  }
}

__global__ void convw_k(const float* __restrict__ src, u16* __restrict__ dst, int n) {
  int i = blockIdx.x * 256 + threadIdx.x;
  if (i < n) dst[i] = f2bf(src[i]);
}

// y[m][n] = sum_k x[m][k] * W[n][k]; y stored bf16. One wave = 16 rows x full N=256.
__global__ void __launch_bounds__(256) gemm_k(const float* __restrict__ x,
                                              const u16* __restrict__ wb,
                                              u16* __restrict__ yb, int M) {
  int wave = (int)((blockIdx.x * 256 + threadIdx.x) >> 6);
  int lane = threadIdx.x & 63;
  int m0 = wave * 16;
  if (m0 >= M) return;
  int ln = lane & 15, q = lane >> 4;
  const float* arow = x + (size_t)(m0 + ln) * F + q * 8;

  f32x4 acc[16];
#pragma unroll
  for (int i = 0; i < 16; i++) acc[i] = (f32x4){0.f, 0.f, 0.f, 0.f};

#pragma unroll
  for (int t = 0; t < 8; t++) {
    const f32x4* a4 = (const f32x4*)(arow + t * 32);
    f32x4 alo = a4[0], ahi = a4[1];
    short8 a;
#pragma unroll
    for (int j = 0; j < 4; j++) {
      a[j]     = (short)f2bf(alo[j]);
      a[4 + j] = (short)f2bf(ahi[j]);
    }
#pragma unroll
    for (int nt = 0; nt < 16; nt++) {
      const short8* bp = (const short8*)(wb + (size_t)(nt * 16 + ln) * F + t * 32 + q * 8);
      acc[nt] = __builtin_amdgcn_mfma_f32_16x16x32_bf16(a, *bp, acc[nt], 0, 0, 0);
    }
  }
#pragma unroll
  for (int nt = 0; nt < 16; nt++) {
#pragma unroll
    for (int r = 0; r < 4; r++) {
      int row = m0 + q * 4 + r;
      yb[(size_t)row * F + nt * 16 + ln] = f2bf(acc[nt][r]);
    }
  }
}

// one wave per node: out[i] = b + sum_e val * y[col]
__global__ void __launch_bounds__(256) gather_k(const int* __restrict__ off,
                                                const int* __restrict__ ccol,
                                                const float* __restrict__ cv,
                                                const u16* __restrict__ yb,
                                                const float* __restrict__ bias,
                                                float* __restrict__ out, int NN) {
  int wave = (int)((blockIdx.x * 256 + threadIdx.x) >> 6);
  int lane = threadIdx.x & 63;
  if (wave >= NN) return;
  int s = off[wave], e = off[wave + 1];
  f32x4 acc = ((const f32x4*)bias)[lane];
  for (int k = s; k < e; k++) {
    int c = ccol[k];
    float v = cv[k];
    u16x4 u = *(const u16x4*)(yb + (size_t)c * F + lane * 4);
    f32x4 xv;
#pragma unroll
    for (int j = 0; j < 4; j++) xv[j] = __uint_as_float((unsigned)u[j] << 16);
    acc += v * xv;
  }
  ((f32x4*)out)[(size_t)wave * 64 + lane] = acc;
}

extern "C" void kernel_launch(void* const* d_in, const int* in_sizes, int n_in,
                              void* d_out, int out_size, void* d_ws, size_t ws_size,
                              hipStream_t stream) {
  const float* x    = (const float*)d_in[0];
  const int*   erow = (const int*)d_in[1];
  const int*   ecol = (const int*)d_in[2];
  const float* eval = (const float*)d_in[3];
  const float* Wm   = (const float*)d_in[4];
  const float* bias = (const float*)d_in[5];
  float* out = (float*)d_out;

  int NN = in_sizes[0] / F;  // 50000
  int E  = in_sizes[1];      // 800000

  char* base = (char*)d_ws;
  size_t o = 0;
  auto carve = [&](size_t bytes) {
    void* p = base + o;
    o += (bytes + 255) & ~(size_t)255;
    return p;
  };
  u16*   yb   = (u16*)carve((size_t)NN * F * 2);   // 25.6 MB bf16 y
  u16*   wb   = (u16*)carve((size_t)F * F * 2);    // 128 KB bf16 W
  int*   off  = (int*)carve((size_t)(NN + 1) * 4); // CSR offsets
  int*   cur  = (int*)carve((size_t)NN * 4);       // scatter cursors
  int*   blks = (int*)carve(256 * 4);              // scan block sums
  int*   ccol = (int*)carve((size_t)E * 4);        // CSR cols
  float* cv   = (float*)carve((size_t)E * 4);      // CSR vals

  int nOff  = NN + 1;
  int nbOff = (nOff + 255) / 256;  // 196 (<=256 required by scan2)
  int nbE   = (E + 255) / 256;

  zero_int<<<nbOff, 256, 0, stream>>>(off, nOff);
  hist_k<<<nbE, 256, 0, stream>>>(erow, off, E);
  scan1_k<<<nbOff, 256, 0, stream>>>(off, blks, nOff);
  scan2_k<<<1, 256, 0, stream>>>(blks, nbOff);
  scan3_k<<<nbOff, 256, 0, stream>>>(off, blks, cur, nOff, NN);
  scatter_k<<<nbE, 256, 0, stream>>>(erow, ecol, eval, cur, ccol, cv, E);

  convw_k<<<(F * F + 255) / 256, 256, 0, stream>>>(Wm, wb, F * F);
  int strips = (NN + 15) / 16;
  gemm_k<<<(strips + 3) / 4, 256, 0, stream>>>(x, wb, yb, NN);

  gather_k<<<(NN + 3) / 4, 256, 0, stream>>>(off, ccol, cv, yb, bias, out, NN);
}

// Round 2
// 326.191 us; speedup vs baseline: 1.0982x; 1.0982x over previous
//
#include <hip/hip_runtime.h>

typedef unsigned short u16;
typedef __attribute__((ext_vector_type(8))) short short8;
typedef __attribute__((ext_vector_type(4))) float f32x4;
typedef __attribute__((ext_vector_type(4))) u16 u16x4;

#define F 256

__device__ __forceinline__ u16 f2bf(float f) {
  unsigned u = __float_as_uint(f);
  unsigned r = u + 0x7fffu + ((u >> 16) & 1u);
  return (u16)(r >> 16);
}

__device__ __forceinline__ f32x4 bf4_to_f32(u16x4 u) {
  f32x4 x;
#pragma unroll
  for (int j = 0; j < 4; j++) x[j] = __uint_as_float((unsigned)u[j] << 16);
  return x;
}

__global__ void zero_int(int* __restrict__ p, int n) {
  int i = blockIdx.x * 256 + threadIdx.x;
  if (i < n) p[i] = 0;
}

__global__ void hist_k(const int* __restrict__ erow, int* __restrict__ off, int E) {
  int e = blockIdx.x * 256 + threadIdx.x;
  if (e < E) atomicAdd(&off[erow[e] + 1], 1);
}

__global__ void scan1_k(int* __restrict__ a, int* __restrict__ blks, int n) {
  __shared__ int s[256];
  int t = threadIdx.x;
  int i = blockIdx.x * 256 + t;
  s[t] = (i < n) ? a[i] : 0;
  __syncthreads();
  for (int d = 1; d < 256; d <<= 1) {
    int v = (t >= d) ? s[t - d] : 0;
    __syncthreads();
    s[t] += v;
    __syncthreads();
  }
  if (i < n) a[i] = s[t];
  if (t == 255) blks[blockIdx.x] = s[255];
}

__global__ void scan2_k(int* __restrict__ blks, int nb) {
  __shared__ int s[256];
  int t = threadIdx.x;
  s[t] = (t < nb) ? blks[t] : 0;
  __syncthreads();
  for (int d = 1; d < 256; d <<= 1) {
    int v = (t >= d) ? s[t - d] : 0;
    __syncthreads();
    s[t] += v;
    __syncthreads();
  }
  if (t < nb) blks[t] = (t == 0) ? 0 : s[t - 1];
}

__global__ void scan3_k(int* __restrict__ a, const int* __restrict__ blks,
                        int* __restrict__ cur, int n, int nn) {
  int i = blockIdx.x * 256 + threadIdx.x;
  if (i < n) {
    int v = a[i] + blks[blockIdx.x];
    a[i] = v;
    if (i < nn) cur[i] = v;
  }
}

// bucket edges into CSR packed (col, val) via atomic cursor
__global__ void scatter_k(const int* __restrict__ erow, const int* __restrict__ ecol,
                          const float* __restrict__ eval, int* __restrict__ cur,
                          int2* __restrict__ epk, int E) {
  int e = blockIdx.x * 256 + threadIdx.x;
  if (e < E) {
    int r = erow[e];
    int p = atomicAdd(&cur[r], 1);
    epk[p] = make_int2(ecol[e], __float_as_int(eval[e]));
  }
}

__global__ void convw_k(const float* __restrict__ src, u16* __restrict__ dst, int n) {
  int i = blockIdx.x * 256 + threadIdx.x;
  if (i < n) dst[i] = f2bf(src[i]);
}

// y[m][n] = sum_k x[m][k] * W[n][k]; y stored bf16. One wave = 16 rows x full N=256.
__global__ void __launch_bounds__(256) gemm_k(const float* __restrict__ x,
                                              const u16* __restrict__ wb,
                                              u16* __restrict__ yb, int M) {
  int wave = (int)((blockIdx.x * 256 + threadIdx.x) >> 6);
  int lane = threadIdx.x & 63;
  int m0 = wave * 16;
  if (m0 >= M) return;
  int ln = lane & 15, q = lane >> 4;
  const float* arow = x + (size_t)(m0 + ln) * F + q * 8;

  f32x4 acc[16];
#pragma unroll
  for (int i = 0; i < 16; i++) acc[i] = (f32x4){0.f, 0.f, 0.f, 0.f};

#pragma unroll
  for (int t = 0; t < 8; t++) {
    const f32x4* a4 = (const f32x4*)(arow + t * 32);
    f32x4 alo = a4[0], ahi = a4[1];
    short8 a;
#pragma unroll
    for (int j = 0; j < 4; j++) {
      a[j]     = (short)f2bf(alo[j]);
      a[4 + j] = (short)f2bf(ahi[j]);
    }
#pragma unroll
    for (int nt = 0; nt < 16; nt++) {
      const short8* bp = (const short8*)(wb + (size_t)(nt * 16 + ln) * F + t * 32 + q * 8);
      acc[nt] = __builtin_amdgcn_mfma_f32_16x16x32_bf16(a, *bp, acc[nt], 0, 0, 0);
    }
  }
#pragma unroll
  for (int nt = 0; nt < 16; nt++) {
#pragma unroll
    for (int r = 0; r < 4; r++) {
      int row = m0 + q * 4 + r;
      yb[(size_t)row * F + nt * 16 + ln] = f2bf(acc[nt][r]);
    }
  }
}

// one wave per node: out[i] = b + sum_e val * y[col]; 4-way unrolled for MLP
__global__ void __launch_bounds__(256) gather_k(const int* __restrict__ off,
                                                const int2* __restrict__ epk,
                                                const u16* __restrict__ yb,
                                                const float* __restrict__ bias,
                                                float* __restrict__ out, int NN) {
  int wave = (int)((blockIdx.x * 256 + threadIdx.x) >> 6);
  int lane = threadIdx.x & 63;
  if (wave >= NN) return;
  int s = off[wave], e = off[wave + 1];

  f32x4 acc0 = ((const f32x4*)bias)[lane];
  f32x4 acc1 = (f32x4){0.f, 0.f, 0.f, 0.f};
  f32x4 acc2 = (f32x4){0.f, 0.f, 0.f, 0.f};
  f32x4 acc3 = (f32x4){0.f, 0.f, 0.f, 0.f};

  int k = s;
  for (; k + 4 <= e; k += 4) {
    int2 p0 = epk[k], p1 = epk[k + 1], p2 = epk[k + 2], p3 = epk[k + 3];
    u16x4 u0 = *(const u16x4*)(yb + (size_t)p0.x * F + lane * 4);
    u16x4 u1 = *(const u16x4*)(yb + (size_t)p1.x * F + lane * 4);
    u16x4 u2 = *(const u16x4*)(yb + (size_t)p2.x * F + lane * 4);
    u16x4 u3 = *(const u16x4*)(yb + (size_t)p3.x * F + lane * 4);
    acc0 += __int_as_float(p0.y) * bf4_to_f32(u0);
    acc1 += __int_as_float(p1.y) * bf4_to_f32(u1);
    acc2 += __int_as_float(p2.y) * bf4_to_f32(u2);
    acc3 += __int_as_float(p3.y) * bf4_to_f32(u3);
  }
  for (; k < e; k++) {
    int2 p = epk[k];
    u16x4 u = *(const u16x4*)(yb + (size_t)p.x * F + lane * 4);
    acc0 += __int_as_float(p.y) * bf4_to_f32(u);
  }
  acc0 += acc1;
  acc2 += acc3;
  acc0 += acc2;
  ((f32x4*)out)[(size_t)wave * 64 + lane] = acc0;
}

extern "C" void kernel_launch(void* const* d_in, const int* in_sizes, int n_in,
                              void* d_out, int out_size, void* d_ws, size_t ws_size,
                              hipStream_t stream) {
  const float* x    = (const float*)d_in[0];
  const int*   erow = (const int*)d_in[1];
  const int*   ecol = (const int*)d_in[2];
  const float* eval = (const float*)d_in[3];
  const float* Wm   = (const float*)d_in[4];
  const float* bias = (const float*)d_in[5];
  float* out = (float*)d_out;

  int NN = in_sizes[0] / F;  // 50000
  int E  = in_sizes[1];      // 800000

  char* base = (char*)d_ws;
  size_t o = 0;
  auto carve = [&](size_t bytes) {
    void* p = base + o;
    o += (bytes + 255) & ~(size_t)255;
    return p;
  };
  u16*   yb   = (u16*)carve((size_t)NN * F * 2);   // 25.6 MB bf16 y
  u16*   wb   = (u16*)carve((size_t)F * F * 2);    // 128 KB bf16 W
  int*   off  = (int*)carve((size_t)(NN + 1) * 4); // CSR offsets
  int*   cur  = (int*)carve((size_t)NN * 4);       // scatter cursors
  int*   blks = (int*)carve(256 * 4);              // scan block sums
  int2*  epk  = (int2*)carve((size_t)E * 8);       // CSR packed (col,val)

  int nOff  = NN + 1;
  int nbOff = (nOff + 255) / 256;  // 196 (<=256 required by scan2)
  int nbE   = (E + 255) / 256;

  zero_int<<<nbOff, 256, 0, stream>>>(off, nOff);
  hist_k<<<nbE, 256, 0, stream>>>(erow, off, E);
  scan1_k<<<nbOff, 256, 0, stream>>>(off, blks, nOff);
  scan2_k<<<1, 256, 0, stream>>>(blks, nbOff);
  scan3_k<<<nbOff, 256, 0, stream>>>(off, blks, cur, nOff, NN);
  scatter_k<<<nbE, 256, 0, stream>>>(erow, ecol, eval, cur, epk, E);

  convw_k<<<(F * F + 255) / 256, 256, 0, stream>>>(Wm, wb, F * F);
  int strips = (NN + 15) / 16;
  gemm_k<<<(strips + 3) / 4, 256, 0, stream>>>(x, wb, yb, NN);

  gather_k<<<(NN + 3) / 4, 256, 0, stream>>>(off, epk, yb, bias, out, NN);
}

// Round 3
// 298.249 us; speedup vs baseline: 1.2011x; 1.0937x over previous
//
#include <hip/hip_runtime.h>

typedef unsigned short u16;
typedef __attribute__((ext_vector_type(8))) short short8;
typedef __attribute__((ext_vector_type(4))) float f32x4;
typedef __attribute__((ext_vector_type(4))) u16 u16x4;

#define F 256

__device__ __forceinline__ u16 f2bf(float f) {
  unsigned u = __float_as_uint(f);
  unsigned r = u + 0x7fffu + ((u >> 16) & 1u);
  return (u16)(r >> 16);
}

__device__ __forceinline__ f32x4 bf4_to_f32(u16x4 u) {
  f32x4 x;
#pragma unroll
  for (int j = 0; j < 4; j++) x[j] = __uint_as_float((unsigned)u[j] << 16);
  return x;
}

__global__ void zero_int(int* __restrict__ p, int n) {
  int i = blockIdx.x * 256 + threadIdx.x;
  if (i < n) p[i] = 0;
}

__global__ void hist_k(const int* __restrict__ erow, int* __restrict__ off, int E) {
  int e = blockIdx.x * 256 + threadIdx.x;
  if (e < E) atomicAdd(&off[erow[e] + 1], 1);
}

__global__ void scan1_k(int* __restrict__ a, int* __restrict__ blks, int n) {
  __shared__ int s[256];
  int t = threadIdx.x;
  int i = blockIdx.x * 256 + t;
  s[t] = (i < n) ? a[i] : 0;
  __syncthreads();
  for (int d = 1; d < 256; d <<= 1) {
    int v = (t >= d) ? s[t - d] : 0;
    __syncthreads();
    s[t] += v;
    __syncthreads();
  }
  if (i < n) a[i] = s[t];
  if (t == 255) blks[blockIdx.x] = s[255];
}

__global__ void scan2_k(int* __restrict__ blks, int nb) {
  __shared__ int s[256];
  int t = threadIdx.x;
  s[t] = (t < nb) ? blks[t] : 0;
  __syncthreads();
  for (int d = 1; d < 256; d <<= 1) {
    int v = (t >= d) ? s[t - d] : 0;
    __syncthreads();
    s[t] += v;
    __syncthreads();
  }
  if (t < nb) blks[t] = (t == 0) ? 0 : s[t - 1];
}

__global__ void scan3_k(int* __restrict__ a, const int* __restrict__ blks,
                        int* __restrict__ cur, int n, int nn) {
  int i = blockIdx.x * 256 + threadIdx.x;
  if (i < n) {
    int v = a[i] + blks[blockIdx.x];
    a[i] = v;
    if (i < nn) cur[i] = v;
  }
}

__global__ void scatter_k(const int* __restrict__ erow, const int* __restrict__ ecol,
                          const float* __restrict__ eval, int* __restrict__ cur,
                          int2* __restrict__ epk, int E) {
  int e = blockIdx.x * 256 + threadIdx.x;
  if (e < E) {
    int r = erow[e];
    int p = atomicAdd(&cur[r], 1);
    epk[p] = make_int2(ecol[e], __float_as_int(eval[e]));
  }
}

__global__ void convw_k(const float* __restrict__ src, u16* __restrict__ dst, int n) {
  int i = blockIdx.x * 256 + threadIdx.x;
  if (i < n) dst[i] = f2bf(src[i]);
}

// y = x @ W^T, y stored bf16. B-resident-in-registers design:
// wave w of each block owns output cols [w*64, w*64+64) (nt = 4w..4w+3) and
// holds all its B fragments (4 nt x 8 t = 128 VGPRs) for the whole kernel.
// Block processes m-tiles (16 rows) round-robin; per tile each wave loads the
// same 16KB A strip (L1-shared), converts to bf16, does 32 MFMAs. No barriers.
__global__ void __launch_bounds__(256, 2) gemm_k(const float* __restrict__ x,
                                                 const u16* __restrict__ wb,
                                                 u16* __restrict__ yb,
                                                 int NT, int stride) {
  int w = (int)(threadIdx.x >> 6);
  int lane = threadIdx.x & 63;
  int ln = lane & 15, q = lane >> 4;

  short8 Bf[4][8];
#pragma unroll
  for (int j = 0; j < 4; j++) {
#pragma unroll
    for (int t = 0; t < 8; t++) {
      Bf[j][t] = *(const short8*)(wb + (size_t)((4 * w + j) * 16 + ln) * F + t * 32 + q * 8);
    }
  }

  for (int mt = blockIdx.x; mt < NT; mt += stride) {
    const float* arow = x + (size_t)(mt * 16 + ln) * F + q * 8;
    f32x4 acc[4];
#pragma unroll
    for (int j = 0; j < 4; j++) acc[j] = (f32x4){0.f, 0.f, 0.f, 0.f};

#pragma unroll
    for (int t = 0; t < 8; t++) {
      const f32x4* a4 = (const f32x4*)(arow + t * 32);
      f32x4 alo = a4[0], ahi = a4[1];
      short8 a;
#pragma unroll
      for (int j = 0; j < 4; j++) {
        a[j]     = (short)f2bf(alo[j]);
        a[4 + j] = (short)f2bf(ahi[j]);
      }
#pragma unroll
      for (int j = 0; j < 4; j++) {
        acc[j] = __builtin_amdgcn_mfma_f32_16x16x32_bf16(a, Bf[j][t], acc[j], 0, 0, 0);
      }
    }

    int m0 = mt * 16;
#pragma unroll
    for (int j = 0; j < 4; j++) {
#pragma unroll
      for (int r = 0; r < 4; r++) {
        yb[(size_t)(m0 + q * 4 + r) * F + (4 * w + j) * 16 + ln] = f2bf(acc[j][r]);
      }
    }
  }
}

// one wave per node: out[i] = b + sum_e val * y[col]; 4-way unrolled for MLP
__global__ void __launch_bounds__(256) gather_k(const int* __restrict__ off,
                                                const int2* __restrict__ epk,
                                                const u16* __restrict__ yb,
                                                const float* __restrict__ bias,
                                                float* __restrict__ out, int NN) {
  int wave = (int)((blockIdx.x * 256 + threadIdx.x) >> 6);
  int lane = threadIdx.x & 63;
  if (wave >= NN) return;
  int s = off[wave], e = off[wave + 1];

  f32x4 acc0 = ((const f32x4*)bias)[lane];
  f32x4 acc1 = (f32x4){0.f, 0.f, 0.f, 0.f};
  f32x4 acc2 = (f32x4){0.f, 0.f, 0.f, 0.f};
  f32x4 acc3 = (f32x4){0.f, 0.f, 0.f, 0.f};

  int k = s;
  for (; k + 4 <= e; k += 4) {
    int2 p0 = epk[k], p1 = epk[k + 1], p2 = epk[k + 2], p3 = epk[k + 3];
    u16x4 u0 = *(const u16x4*)(yb + (size_t)p0.x * F + lane * 4);
    u16x4 u1 = *(const u16x4*)(yb + (size_t)p1.x * F + lane * 4);
    u16x4 u2 = *(const u16x4*)(yb + (size_t)p2.x * F + lane * 4);
    u16x4 u3 = *(const u16x4*)(yb + (size_t)p3.x * F + lane * 4);
    acc0 += __int_as_float(p0.y) * bf4_to_f32(u0);
    acc1 += __int_as_float(p1.y) * bf4_to_f32(u1);
    acc2 += __int_as_float(p2.y) * bf4_to_f32(u2);
    acc3 += __int_as_float(p3.y) * bf4_to_f32(u3);
  }
  for (; k < e; k++) {
    int2 p = epk[k];
    u16x4 u = *(const u16x4*)(yb + (size_t)p.x * F + lane * 4);
    acc0 += __int_as_float(p.y) * bf4_to_f32(u);
  }
  acc0 += acc1;
  acc2 += acc3;
  acc0 += acc2;
  ((f32x4*)out)[(size_t)wave * 64 + lane] = acc0;
}

extern "C" void kernel_launch(void* const* d_in, const int* in_sizes, int n_in,
                              void* d_out, int out_size, void* d_ws, size_t ws_size,
                              hipStream_t stream) {
  const float* x    = (const float*)d_in[0];
  const int*   erow = (const int*)d_in[1];
  const int*   ecol = (const int*)d_in[2];
  const float* eval = (const float*)d_in[3];
  const float* Wm   = (const float*)d_in[4];
  const float* bias = (const float*)d_in[5];
  float* out = (float*)d_out;

  int NN = in_sizes[0] / F;  // 50000
  int E  = in_sizes[1];      // 800000

  char* base = (char*)d_ws;
  size_t o = 0;
  auto carve = [&](size_t bytes) {
    void* p = base + o;
    o += (bytes + 255) & ~(size_t)255;
    return p;
  };
  u16*   yb   = (u16*)carve((size_t)NN * F * 2);   // 25.6 MB bf16 y
  u16*   wb   = (u16*)carve((size_t)F * F * 2);    // 128 KB bf16 W
  int*   off  = (int*)carve((size_t)(NN + 1) * 4); // CSR offsets
  int*   cur  = (int*)carve((size_t)NN * 4);       // scatter cursors
  int*   blks = (int*)carve(256 * 4);              // scan block sums
  int2*  epk  = (int2*)carve((size_t)E * 8);       // CSR packed (col,val)

  int nOff  = NN + 1;
  int nbOff = (nOff + 255) / 256;  // 196 (<=256 required by scan2)
  int nbE   = (E + 255) / 256;

  zero_int<<<nbOff, 256, 0, stream>>>(off, nOff);
  hist_k<<<nbE, 256, 0, stream>>>(erow, off, E);
  scan1_k<<<nbOff, 256, 0, stream>>>(off, blks, nOff);
  scan2_k<<<1, 256, 0, stream>>>(blks, nbOff);
  scan3_k<<<nbOff, 256, 0, stream>>>(off, blks, cur, nOff, NN);
  scatter_k<<<nbE, 256, 0, stream>>>(erow, ecol, eval, cur, epk, E);

  convw_k<<<(F * F + 255) / 256, 256, 0, stream>>>(Wm, wb, F * F);
  int NT = (NN + 15) / 16;  // 3125 m-tiles
  int nBlocks = 512;        // 2 blocks/CU at 8 waves/CU
  gemm_k<<<nBlocks, 256, 0, stream>>>(x, wb, yb, NT, nBlocks);

  gather_k<<<(NN + 3) / 4, 256, 0, stream>>>(off, epk, yb, bias, out, NN);
}